// Round 2
// baseline (65.177 us; speedup 1.0000x reference)
//
#include <hip/hip_runtime.h>

// Problem constants (from setup_inputs): B=256 batches, N=512 keypoints.
#define BATCH 256
#define NPTS  512
#define TPB   256            // 2 points per thread
#define PPT   (NPTS / TPB)
#define CENTER_X 0.5f

// Single fused kernel, one block per batch.
// Per symmetric class k in {0,1,2} with u = x - cx:
//   sum_{i<j} (x_i+x_j-2cx)^2 = (m-2)*su2 + su^2
//   sum_{i<j} (y_i-y_j)^2     = m*sy2 - sy^2
//   pairs                     = m*(m-1)/2
// Each block stores its (total, count) partial, then the last block (by
// ticket) reduces all 256 partials in a fixed order (deterministic) and
// writes the mean. ticket must be zeroed by a 4-byte memset before launch.
__global__ __launch_bounds__(TPB) void sym_fused(
    const float* __restrict__ kp,   // [B, N, 2]
    const int* __restrict__ cls,    // [B, N]
    float* __restrict__ out,
    int* __restrict__ ticket,
    float* __restrict__ totals,     // [BATCH]
    float* __restrict__ counts) {   // [BATCH]
  const int b = blockIdx.x;
  const int t = threadIdx.x;
  const int wave = t >> 6;
  const int lane = t & 63;

  float v[15];
#pragma unroll
  for (int i = 0; i < 15; ++i) v[i] = 0.0f;

#pragma unroll
  for (int p = 0; p < PPT; ++p) {
    const int idx = b * NPTS + p * TPB + t;
    const float2 q = ((const float2*)kp)[idx];
    const int c = cls[idx];
    const float u = q.x - CENTER_X;
    const float y = q.y;
#pragma unroll
    for (int k = 0; k < 3; ++k) {
      const float sel = (c == k) ? 1.0f : 0.0f;
      v[5 * k + 0] += sel * u;
      v[5 * k + 1] += sel * u * u;
      v[5 * k + 2] += sel * y;
      v[5 * k + 3] += sel * y * y;
      v[5 * k + 4] += sel;
    }
  }

  // 64-lane butterfly reduce all 15 values
#pragma unroll
  for (int off = 32; off >= 1; off >>= 1) {
#pragma unroll
    for (int i = 0; i < 15; ++i) v[i] += __shfl_down(v[i], off, 64);
  }

  __shared__ float lds[TPB / 64][15];
  __shared__ int is_last;
  if (lane == 0) {
#pragma unroll
    for (int i = 0; i < 15; ++i) lds[wave][i] = v[i];
  }
  __syncthreads();

  if (t == 0) {
    float total = 0.0f, count = 0.0f;
#pragma unroll
    for (int k = 0; k < 3; ++k) {
      float su = 0.f, su2 = 0.f, sy = 0.f, sy2 = 0.f, m = 0.f;
#pragma unroll
      for (int w = 0; w < TPB / 64; ++w) {
        su  += lds[w][5 * k + 0];
        su2 += lds[w][5 * k + 1];
        sy  += lds[w][5 * k + 2];
        sy2 += lds[w][5 * k + 3];
        m   += lds[w][5 * k + 4];
      }
      total += (m - 2.0f) * su2 + su * su + m * sy2 - sy * sy;
      count += 0.5f * m * (m - 1.0f);
    }
    __hip_atomic_store(&totals[b], total, __ATOMIC_RELAXED, __HIP_MEMORY_SCOPE_AGENT);
    __hip_atomic_store(&counts[b], count, __ATOMIC_RELAXED, __HIP_MEMORY_SCOPE_AGENT);
    __threadfence();  // release partials before the ticket bump
    const int old = __hip_atomic_fetch_add(ticket, 1, __ATOMIC_ACQ_REL,
                                           __HIP_MEMORY_SCOPE_AGENT);
    is_last = (old == (int)gridDim.x - 1);
  }
  __syncthreads();

  if (is_last) {  // block-uniform: only the final block enters
    float T = __hip_atomic_load(&totals[t], __ATOMIC_RELAXED, __HIP_MEMORY_SCOPE_AGENT);
    float C = __hip_atomic_load(&counts[t], __ATOMIC_RELAXED, __HIP_MEMORY_SCOPE_AGENT);
#pragma unroll
    for (int off = 32; off >= 1; off >>= 1) {
      T += __shfl_down(T, off, 64);
      C += __shfl_down(C, off, 64);
    }
    __shared__ float lt[TPB / 64], lc[TPB / 64];
    if (lane == 0) { lt[wave] = T; lc[wave] = C; }
    __syncthreads();
    if (t == 0) {
      float Ts = 0.f, Cs = 0.f;
#pragma unroll
      for (int w = 0; w < TPB / 64; ++w) { Ts += lt[w]; Cs += lc[w]; }
      out[0] = Ts / fmaxf(Cs, 1.0f);
    }
  }
}

extern "C" void kernel_launch(void* const* d_in, const int* in_sizes, int n_in,
                              void* d_out, int out_size, void* d_ws, size_t ws_size,
                              hipStream_t stream) {
  const float* kp = (const float*)d_in[0];   // [B, N, 2] float32
  const int* cls = (const int*)d_in[1];      // [B, N] int32
  float* out = (float*)d_out;

  int* ticket = (int*)d_ws;                  // 4 B at offset 0
  float* totals = (float*)d_ws + 32;         // 128 B offset (own cache line)
  float* counts = totals + BATCH;

  hipMemsetAsync(d_ws, 0, 4, stream);        // zero the ticket (capture-legal)
  sym_fused<<<BATCH, TPB, 0, stream>>>(kp, cls, out, ticket, totals, counts);
}

// Round 3
// 57.300 us; speedup vs baseline: 1.1375x; 1.1375x over previous
//
#include <hip/hip_runtime.h>

// Problem constants (from setup_inputs): B=256 batches, N=512 keypoints.
#define BATCH 256
#define NPTS  512
#define TPB   256            // 2 points per thread
#define PPT   (NPTS / TPB)
#define CENTER_X 0.5f

// Kernel 1: one block per batch, 256 threads, 2 points/thread.
// Per symmetric class k in {0,1,2} with u = x - cx:
//   sum_{i<j} (x_i+x_j-2cx)^2 = (m-2)*su2 + su^2
//   sum_{i<j} (y_i-y_j)^2     = m*sy2 - sy^2
//   pairs                     = m*(m-1)/2
// Writes per-batch total to ws[b], per-batch pair count to ws[BATCH+b].
__global__ __launch_bounds__(TPB) void sym_batch_reduce(
    const float* __restrict__ kp,   // [B, N, 2]
    const int* __restrict__ cls,    // [B, N]
    float* __restrict__ ws) {
  const int b = blockIdx.x;
  const int t = threadIdx.x;
  const int wave = t >> 6;
  const int lane = t & 63;

  float v[15];
#pragma unroll
  for (int i = 0; i < 15; ++i) v[i] = 0.0f;

#pragma unroll
  for (int p = 0; p < PPT; ++p) {
    const int idx = b * NPTS + p * TPB + t;
    const float2 q = ((const float2*)kp)[idx];
    const int c = cls[idx];
    const float u = q.x - CENTER_X;
    const float y = q.y;
#pragma unroll
    for (int k = 0; k < 3; ++k) {
      const float sel = (c == k) ? 1.0f : 0.0f;
      v[5 * k + 0] += sel * u;
      v[5 * k + 1] += sel * u * u;
      v[5 * k + 2] += sel * y;
      v[5 * k + 3] += sel * y * y;
      v[5 * k + 4] += sel;
    }
  }

  // 64-lane butterfly reduce all 15 values
#pragma unroll
  for (int off = 32; off >= 1; off >>= 1) {
#pragma unroll
    for (int i = 0; i < 15; ++i) v[i] += __shfl_down(v[i], off, 64);
  }

  __shared__ float lds[TPB / 64][15];
  if (lane == 0) {
#pragma unroll
    for (int i = 0; i < 15; ++i) lds[wave][i] = v[i];
  }
  __syncthreads();

  if (t == 0) {
    float total = 0.0f, count = 0.0f;
#pragma unroll
    for (int k = 0; k < 3; ++k) {
      float su = 0.f, su2 = 0.f, sy = 0.f, sy2 = 0.f, m = 0.f;
#pragma unroll
      for (int w = 0; w < TPB / 64; ++w) {
        su  += lds[w][5 * k + 0];
        su2 += lds[w][5 * k + 1];
        sy  += lds[w][5 * k + 2];
        sy2 += lds[w][5 * k + 3];
        m   += lds[w][5 * k + 4];
      }
      total += (m - 2.0f) * su2 + su * su + m * sy2 - sy * sy;
      count += 0.5f * m * (m - 1.0f);
    }
    ws[b] = total;
    ws[BATCH + b] = count;
  }
}

// Kernel 2: single 256-thread block reduces the per-batch results and
// writes the final mean.
__global__ __launch_bounds__(BATCH) void sym_final_reduce(
    const float* __restrict__ ws, float* __restrict__ out) {
  const int t = threadIdx.x;
  const int wave = t >> 6;
  const int lane = t & 63;
  float total = ws[t];
  float count = ws[BATCH + t];

#pragma unroll
  for (int off = 32; off >= 1; off >>= 1) {
    total += __shfl_down(total, off, 64);
    count += __shfl_down(count, off, 64);
  }

  __shared__ float lt[BATCH / 64], lc[BATCH / 64];
  if (lane == 0) { lt[wave] = total; lc[wave] = count; }
  __syncthreads();

  if (t == 0) {
    float T = 0.f, C = 0.f;
#pragma unroll
    for (int w = 0; w < BATCH / 64; ++w) { T += lt[w]; C += lc[w]; }
    out[0] = T / fmaxf(C, 1.0f);
  }
}

extern "C" void kernel_launch(void* const* d_in, const int* in_sizes, int n_in,
                              void* d_out, int out_size, void* d_ws, size_t ws_size,
                              hipStream_t stream) {
  const float* kp = (const float*)d_in[0];   // [B, N, 2] float32
  const int* cls = (const int*)d_in[1];      // [B, N] int32
  float* out = (float*)d_out;
  float* ws = (float*)d_ws;                  // needs 2*BATCH floats = 2 KiB

  sym_batch_reduce<<<BATCH, TPB, 0, stream>>>(kp, cls, ws);
  sym_final_reduce<<<1, BATCH, 0, stream>>>(ws, out);
}